// Round 3
// baseline (77.710 us; speedup 1.0000x reference)
//
#include <hip/hip_runtime.h>

// SU2 attention, MI355X — round 3.
// Math: logits.real = dot4(normed_i, normed_j); x in [-0.7071,0.7071] so
// softmax needs NO max-subtraction -> partials combine by plain sum.
// R3 changes: (a) store raw spinor table vtab + inv-norm table ntab, fold
// SCALE*log2(e) into the query fragment -> exponent = dot(qc, v_j)*inv_j;
// (b) float2 element-wise math to get v_pk_fma_f32 dual-rate fp32.
// Output is PLANAR: d_out = [32768 reals (i,h,d)], then [32768 imags].

#define S 2048
#define H 8
#define QR 8   // queries per wave (register-tiled)

__device__ inline float fast_exp2(float x) {
#if __has_builtin(__builtin_amdgcn_exp2f)
    return __builtin_amdgcn_exp2f(x);
#else
    return exp2f(x);
#endif
}
__device__ inline float2 f2mul(float2 a, float2 b) {
    return make_float2(a.x * b.x, a.y * b.y);
}
__device__ inline float2 f2fma(float2 a, float2 b, float2 c) {
    return make_float2(fmaf(a.x, b.x, c.x), fmaf(a.y, b.y, c.y));
}

// Repack: vtab[h*2048+j] = raw spinor (re0,im0,re1,im1); ntab = 1/||spinor||.
__global__ __launch_bounds__(256) void su2_prep(const float* __restrict__ re,
                                                const float* __restrict__ im,
                                                float4* __restrict__ vtab,
                                                float* __restrict__ ntab) {
    int t = blockIdx.x * 256 + threadIdx.x;   // t = h*2048 + j
    int h = t >> 11;
    int j = t & 2047;
    const float2* re2 = (const float2*)re;    // input layout (j, h, d)
    const float2* im2 = (const float2*)im;
    float2 r = re2[j * H + h];
    float2 m = im2[j * H + h];
    float ss = r.x * r.x + m.x * m.x + r.y * r.y + m.y * m.y;
    vtab[t] = make_float4(r.x, m.x, r.y, m.y);
    ntab[t] = rsqrtf(ss);
}

// One wave per 8 queries; j split over 64 lanes (32 iters).
// grid = (64, 8): x = query group (4 waves x 8 q), y = head.
__global__ __launch_bounds__(256) void su2_attn(const float4* __restrict__ vtab,
                                                const float* __restrict__ ntab,
                                                float2* __restrict__ outr,
                                                float2* __restrict__ outi) {
    const int h    = blockIdx.y;
    const int lane = threadIdx.x & 63;
    const int wave = threadIdx.x >> 6;
    const int i_base = (blockIdx.x * 4 + wave) * QR;

    const float4* __restrict__ vt = vtab + (h << 11);
    const float*  __restrict__ nt = ntab + (h << 11);

    // c = SCALE * log2(e); folded into the query fragment.
    const float c = 0.70710678118654752440f * 1.44269504088896340736f;

    float2 qc0[QR], qc1[QR];
#pragma unroll
    for (int r = 0; r < QR; ++r) {
        float4 v = vt[i_base + r];
        float  s = nt[i_base + r] * c;
        qc0[r] = make_float2(v.x * s, v.y * s);
        qc1[r] = make_float2(v.z * s, v.w * s);
    }

    float  l[QR];
    float2 a0[QR], a1[QR];
#pragma unroll
    for (int r = 0; r < QR; ++r) {
        l[r]  = 0.f;
        a0[r] = make_float2(0.f, 0.f);
        a1[r] = make_float2(0.f, 0.f);
    }

#pragma unroll 4
    for (int jj = 0; jj < S / 64; ++jj) {
        int j = jj * 64 + lane;
        float4 v   = vt[j];
        float  inv = nt[j];
        float2 v0 = make_float2(v.x, v.y);
        float2 v1 = make_float2(v.z, v.w);
#pragma unroll
        for (int r = 0; r < QR; ++r) {
            float2 d2 = f2fma(qc1[r], v1, f2mul(qc0[r], v0));
            float  p  = fast_exp2((d2.x + d2.y) * inv);
            l[r] += p;
            float2 pp = make_float2(p, p);
            a0[r] = f2fma(pp, v0, a0[r]);
            a1[r] = f2fma(pp, v1, a1[r]);
        }
    }

    // Butterfly sum all-reduce across 64 lanes (plain sums — no max state)
#pragma unroll
    for (int r = 0; r < QR; ++r) {
#pragma unroll
        for (int m = 32; m >= 1; m >>= 1) {
            l[r]    += __shfl_xor(l[r], m, 64);
            a0[r].x += __shfl_xor(a0[r].x, m, 64);
            a0[r].y += __shfl_xor(a0[r].y, m, 64);
            a1[r].x += __shfl_xor(a1[r].x, m, 64);
            a1[r].y += __shfl_xor(a1[r].y, m, 64);
        }
    }

    if (lane == 0) {
#pragma unroll
        for (int r = 0; r < QR; ++r) {
            float invl = 1.0f / l[r];
            int i = i_base + r;
            // planar: real plane then imag plane, each (i, h, d) as float2
            outr[i * H + h] = make_float2(a0[r].x * invl, a1[r].x * invl);
            outi[i * H + h] = make_float2(a0[r].y * invl, a1[r].y * invl);
        }
    }
}

extern "C" void kernel_launch(void* const* d_in, const int* in_sizes, int n_in,
                              void* d_out, int out_size, void* d_ws, size_t ws_size,
                              hipStream_t stream) {
    const float* re = (const float*)d_in[0];
    const float* im = (const float*)d_in[1];
    float4* vtab = (float4*)d_ws;            // 16384 float4 = 256 KB
    float*  ntab = (float*)(vtab + S * H);   // + 64 KB
    float2* outr = (float2*)d_out;           // reals: 16384 float2
    float2* outi = outr + S * H;             // imags

    su2_prep<<<dim3(64), dim3(256), 0, stream>>>(re, im, vtab, ntab);
    su2_attn<<<dim3(S / 32, H), dim3(256), 0, stream>>>(vtab, ntab, outr, outi);
}

// Round 4
// 72.101 us; speedup vs baseline: 1.0778x; 1.0778x over previous
//
#include <hip/hip_runtime.h>

// SU2 attention, MI355X — round 4: single fused kernel.
// Math: logits.real = dot4(q_hat, k_hat); |x*SCALE| <= 0.7071 so softmax
// needs NO max-subtraction -> partials combine by plain sum.
// Per-head table (raw spinor float4 + inv-norm) staged in LDS (40 KB);
// each block builds its own copy — kills prep kernel + d_ws round-trip.
// Output PLANAR: d_out = [32768 reals (i,h,d)], then [32768 imags].

#define S 2048
#define H 8
#define QR 8   // queries per wave (register-tiled)

__device__ inline float fast_exp2(float x) {
#if __has_builtin(__builtin_amdgcn_exp2f)
    return __builtin_amdgcn_exp2f(x);
#else
    return exp2f(x);
#endif
}
__device__ inline float2 f2mul(float2 a, float2 b) {
    return make_float2(a.x * b.x, a.y * b.y);
}
__device__ inline float2 f2fma(float2 a, float2 b, float2 c) {
    return make_float2(fmaf(a.x, b.x, c.x), fmaf(a.y, b.y, c.y));
}

// grid = (64, 8): x = query group (4 waves x 8 q = 32 q/block), y = head.
__global__ __launch_bounds__(256) void su2_attn_fused(
        const float* __restrict__ re, const float* __restrict__ im,
        float2* __restrict__ outr, float2* __restrict__ outi) {
    __shared__ float4 vt[S];   // raw spinor (re0, im0, re1, im1), 32 KB
    __shared__ float  nt[S];   // 1/||spinor||, 8 KB

    const int h    = blockIdx.y;
    const int lane = threadIdx.x & 63;
    const int wave = threadIdx.x >> 6;
    const int i_base = (blockIdx.x * 4 + wave) * QR;

    // ---- stage this head's table into LDS (strided 8B loads, L2-resident)
    const float2* __restrict__ re2 = (const float2*)re;  // input (j, h, d)
    const float2* __restrict__ im2 = (const float2*)im;
#pragma unroll
    for (int k = 0; k < S / 256; ++k) {
        int j = k * 256 + threadIdx.x;
        float2 r = re2[j * H + h];
        float2 m = im2[j * H + h];
        float ss = r.x * r.x + m.x * m.x + r.y * r.y + m.y * m.y;
        vt[j] = make_float4(r.x, m.x, r.y, m.y);
        nt[j] = rsqrtf(ss);
    }
    __syncthreads();

    // ---- query fragments with SCALE*log2(e)*inv_norm folded in
    const float c = 0.70710678118654752440f * 1.44269504088896340736f;
    float2 qc0[QR], qc1[QR];
#pragma unroll
    for (int r = 0; r < QR; ++r) {
        float4 v = vt[i_base + r];              // LDS broadcast
        float  s = nt[i_base + r] * c;
        qc0[r] = make_float2(v.x * s, v.y * s);
        qc1[r] = make_float2(v.z * s, v.w * s);
    }

    float  l[QR];
    float2 a0[QR], a1[QR];
#pragma unroll
    for (int r = 0; r < QR; ++r) {
        l[r]  = 0.f;
        a0[r] = make_float2(0.f, 0.f);
        a1[r] = make_float2(0.f, 0.f);
    }

    // ---- main loop: j split over 64 lanes, 32 iters
#pragma unroll 4
    for (int jj = 0; jj < S / 64; ++jj) {
        int j = jj * 64 + lane;
        float4 v   = vt[j];                     // ds_read_b128, conflict-free
        float  inv = nt[j];
        float2 v0 = make_float2(v.x, v.y);
        float2 v1 = make_float2(v.z, v.w);
#pragma unroll
        for (int r = 0; r < QR; ++r) {
            float2 d2 = f2fma(qc1[r], v1, f2mul(qc0[r], v0));
            float  p  = fast_exp2((d2.x + d2.y) * inv);
            l[r] += p;
            float2 pp = make_float2(p, p);
            a0[r] = f2fma(pp, v0, a0[r]);
            a1[r] = f2fma(pp, v1, a1[r]);
        }
    }

    // ---- butterfly sum all-reduce across 64 lanes (plain sums)
#pragma unroll
    for (int r = 0; r < QR; ++r) {
#pragma unroll
        for (int m = 32; m >= 1; m >>= 1) {
            l[r]    += __shfl_xor(l[r], m, 64);
            a0[r].x += __shfl_xor(a0[r].x, m, 64);
            a0[r].y += __shfl_xor(a0[r].y, m, 64);
            a1[r].x += __shfl_xor(a1[r].x, m, 64);
            a1[r].y += __shfl_xor(a1[r].y, m, 64);
        }
    }

    if (lane == 0) {
#pragma unroll
        for (int r = 0; r < QR; ++r) {
            float invl = 1.0f / l[r];
            int i = i_base + r;
            // planar: real plane then imag plane, each (i, h, d) as float2
            outr[i * H + h] = make_float2(a0[r].x * invl, a1[r].x * invl);
            outi[i * H + h] = make_float2(a0[r].y * invl, a1[r].y * invl);
        }
    }
}

extern "C" void kernel_launch(void* const* d_in, const int* in_sizes, int n_in,
                              void* d_out, int out_size, void* d_ws, size_t ws_size,
                              hipStream_t stream) {
    const float* re = (const float*)d_in[0];
    const float* im = (const float*)d_in[1];
    float2* outr = (float2*)d_out;    // reals: 16384 float2
    float2* outi = outr + S * H;      // imags
    (void)d_ws; (void)ws_size;

    su2_attn_fused<<<dim3(S / 32, H), dim3(256), 0, stream>>>(re, im, outr, outi);
}